// Round 3
// baseline (1135.680 us; speedup 1.0000x reference)
//
#include <hip/hip_runtime.h>

typedef __attribute__((ext_vector_type(8))) short bf16x8;
typedef __attribute__((ext_vector_type(4))) float f32x4;

#define MFMA_B16(A,B,C) __builtin_amdgcn_mfma_f32_16x16x32_bf16((A),(B),(C),0,0,0)

// ---- fragment layout constants (units: fragments of 1KB = 64 lanes * 8 bf16) ----
#define FO_ENC1 0
#define FO_PRI1 48
#define FO_DEC1 88
#define FO_GIH  136
#define FO_GHH  184
#define FO_ENC2 280
#define FO_PRI2 312
#define FO_DEC2 344
#define FO_MS   376
#define FO_DECMS 408
#define NFRAG   412

// padded LDS strides (odd dword multiples -> ~2-way max bank aliasing)
#define MS  202   // master stride in shorts (404B = 101 dw, odd)
#define TS 138    // t1/h tile stride in shorts (276B = 69 dw, odd)

__device__ __forceinline__ unsigned short f2bf(float f) {
  union { float f; unsigned u; } v; v.f = f;
  unsigned r = (v.u + 0x7fffu + ((v.u >> 16) & 1u)) >> 16;
  return (unsigned short)r;
}
__device__ __forceinline__ float bf2f(unsigned short h) {
  union { unsigned u; float f; } v; v.u = ((unsigned)h) << 16;
  return v.f;
}
__device__ __forceinline__ float sigm_(float x) { return 1.f / (1.f + __expf(-x)); }
__device__ __forceinline__ float tanh_(float x) {
  x = fminf(fmaxf(x, -15.f), 15.f);
  float e = __expf(-2.f * x);
  return (1.f - e) / (1.f + e);
}
__device__ __forceinline__ float splus_(float x) {
  return fmaxf(x, 0.f) + log1pf(__expf(-fabsf(x)));
}
// pin a value into VGPRs: opaque def defeats rematerialization of the load
__device__ __forceinline__ void pin(bf16x8 &x) {
  f32x4 &r = reinterpret_cast<f32x4&>(x);
  asm volatile("" : "+v"(r));
}
__device__ __forceinline__ void pinf(float &x) { asm volatile("" : "+v"(x)); }

// ============================ PREP KERNEL ============================
// Master activation k-layout: [x:0..1 | z:2..33 | y:34..43 | pad:44..63 | h:64..191]
// Fragment (64 lanes x 8 bf16): lane l, elem j -> B[mk = kb*32 + (l>>4)*8 + j][n = nt*16 + (l&15)]
__global__ void prep_kernel(const float* __restrict__ ew1, const float* __restrict__ pw1,
                            const float* __restrict__ dw1, const float* __restrict__ wih,
                            const float* __restrict__ whh, const float* __restrict__ ew2,
                            const float* __restrict__ pw2, const float* __restrict__ dw2,
                            const float* __restrict__ emw, const float* __restrict__ esw,
                            const float* __restrict__ pmw, const float* __restrict__ psw,
                            const float* __restrict__ dmw, const float* __restrict__ dsw,
                            unsigned short* __restrict__ ws)
{
  int blk = blockIdx.x;
  int a = blk / NFRAG, f = blk % NFRAG;
  int l = threadIdx.x, lg = l >> 4, ln = l & 15;
  float v[8];

  if (f < FO_PRI1) {                       // enc1: rows [x:0-1, y:2-11, h:12-139], N=128
    int fi = f, nt = fi / 6, kb = fi % 6, n = nt * 16 + ln;
#pragma unroll
    for (int j = 0; j < 8; ++j) {
      int mk = kb * 32 + lg * 8 + j;
      int r = (mk < 2) ? mk : (mk >= 34 && mk < 44) ? 2 + (mk - 34)
            : (mk >= 64) ? 12 + (mk - 64) : -1;
      v[j] = (r >= 0) ? ew1[((size_t)a * 140 + r) * 128 + n] : 0.f;
    }
  } else if (f < FO_DEC1) {                // pri1: rows [y:0-9, h:10-137]
    int fi = f - FO_PRI1, nt = fi / 5, kb = 1 + fi % 5, n = nt * 16 + ln;
#pragma unroll
    for (int j = 0; j < 8; ++j) {
      int mk = kb * 32 + lg * 8 + j;
      int r = (mk >= 34 && mk < 44) ? (mk - 34) : (mk >= 64) ? 10 + (mk - 64) : -1;
      v[j] = (r >= 0) ? pw1[((size_t)a * 138 + r) * 128 + n] : 0.f;
    }
  } else if (f < FO_GIH) {                 // dec1: rows [y:0-9, z:10-41, h:42-169]
    int fi = f - FO_DEC1, nt = fi / 6, kb = fi % 6, n = nt * 16 + ln;
#pragma unroll
    for (int j = 0; j < 8; ++j) {
      int mk = kb * 32 + lg * 8 + j;
      int r = (mk >= 2 && mk < 34) ? 10 + (mk - 2) : (mk >= 34 && mk < 44) ? (mk - 34)
            : (mk >= 64) ? 42 + (mk - 64) : -1;
      v[j] = (r >= 0) ? dw1[((size_t)a * 170 + r) * 128 + n] : 0.f;
    }
  } else if (f < FO_GHH) {                 // gru_ih: rows [x:0-1, z:2-33], N=384
    int fi = f - FO_GIH, nt = fi / 2, kb = fi % 2, n = nt * 16 + ln;
#pragma unroll
    for (int j = 0; j < 8; ++j) {
      int mk = kb * 32 + lg * 8 + j;
      v[j] = (mk < 34) ? wih[((size_t)a * 34 + mk) * 384 + n] : 0.f;
    }
  } else if (f < FO_ENC2) {                // gru_hh: K=128 (master kb2..5), N=384
    int fi = f - FO_GHH, nt = fi / 4, kb = fi % 4, n = nt * 16 + ln;
#pragma unroll
    for (int j = 0; j < 8; ++j) {
      int r = kb * 32 + lg * 8 + j;
      v[j] = whh[((size_t)a * 128 + r) * 384 + n];
    }
  } else if (f < FO_DEC2) {                // enc2 / pri2
    int fi = f - FO_ENC2;
    const float* W = (fi < 32) ? ew2 : pw2;
    fi &= 31;
    int nt = fi / 4, kb = fi % 4, n = nt * 16 + ln;
#pragma unroll
    for (int j = 0; j < 8; ++j) {
      int r = kb * 32 + lg * 8 + j;
      v[j] = W[((size_t)a * 128 + r) * 128 + n];
    }
  } else if (f < FO_MS) {                  // dec2
    int fi = f - FO_DEC2, nt = fi / 4, kb = fi % 4, n = nt * 16 + ln;
#pragma unroll
    for (int j = 0; j < 8; ++j) {
      int r = kb * 32 + lg * 8 + j;
      v[j] = dw2[((size_t)a * 128 + r) * 128 + n];
    }
  } else if (f < FO_DECMS) {               // enc_m / enc_s / pri_m / pri_s (N=32)
    int fi = f - FO_MS, mat = fi / 8, rem = fi % 8, nt = rem / 4, kb = rem % 4;
    int n = nt * 16 + ln;
    const float* W = (mat == 0) ? emw : (mat == 1) ? esw : (mat == 2) ? pmw : psw;
#pragma unroll
    for (int j = 0; j < 8; ++j) {
      int r = kb * 32 + lg * 8 + j;
      v[j] = W[((size_t)a * 128 + r) * 32 + n];
    }
  } else {                                 // dec m/s packed: cols 0,1 = mw; 2,3 = sw; rest 0
    int kb = f - FO_DECMS;
#pragma unroll
    for (int j = 0; j < 8; ++j) {
      int r = kb * 32 + lg * 8 + j;
      v[j] = (ln < 2) ? dmw[((size_t)a * 128 + r) * 2 + ln]
           : (ln < 4) ? dsw[((size_t)a * 128 + r) * 2 + (ln - 2)] : 0.f;
    }
  }
  unsigned short* dst = ws + (size_t)blk * 512 + l * 8;
#pragma unroll
  for (int j = 0; j < 8; ++j) dst[j] = f2bf(v[j]);
}

// ============================ MAIN KERNEL ============================
// grid (32, 5): blockIdx.x = batch tile (16 rows), blockIdx.y = agent. 512 threads = 8 waves.
// Weights: ghh/ms/decms pinned in LDS; everything else pinned in registers (asm pin).
// Phases per step (5 barriers): A(enc1,pri1 | w0: prev decms+NLL) | B(enc2,pri2)
//   | C(w0/1: enc heads+z, w2/3: pri heads, w4-7: gru_hh) | D(w0-3: dec1+KL, w4-7: gru_ih+GRU)
//   | E(dec2, h-write, stage y/x(t+1))
__global__ __launch_bounds__(512, 2) void vrnn_main(
    const float* __restrict__ states, const float* __restrict__ eps,
    const float* __restrict__ eb1, const float* __restrict__ eb2,
    const float* __restrict__ emb, const float* __restrict__ esb,
    const float* __restrict__ pb1, const float* __restrict__ pb2,
    const float* __restrict__ pmb, const float* __restrict__ psb,
    const float* __restrict__ db1, const float* __restrict__ db2,
    const float* __restrict__ dmb, const float* __restrict__ dsb,
    const float* __restrict__ bih, const float* __restrict__ bhh,
    const unsigned short* __restrict__ frags, float* __restrict__ out)
{
  const int a = blockIdx.y;
  const int b0 = blockIdx.x * 16;
  const int tid = threadIdx.x;
  const int w = tid >> 6, l = tid & 63, lg = l >> 4, ln = l & 15;

  __shared__ __align__(16) unsigned short ghh_lds[96 * 512];
  __shared__ __align__(16) unsigned short ms_lds[32 * 512];
  __shared__ __align__(16) unsigned short dms_lds[4 * 512];
  __shared__ __align__(16) unsigned short master[16 * MS];
  __shared__ __align__(16) unsigned short t1e[16 * TS], t1p[16 * TS];  // t1d aliases t1e
  __shared__ __align__(16) unsigned short he[16 * TS], hp[16 * TS];    // hd aliases he
  __shared__ float msbuf[2][16][33];
  __shared__ float red[16];

  const unsigned short* fa = frags + (size_t)a * NFRAG * 512;

  // ---- pin LDS weight sets (once)
  {
    const uint4* s1 = (const uint4*)(fa + (size_t)FO_GHH * 512);
    uint4* d1 = (uint4*)ghh_lds;
    for (int i = tid; i < 96 * 64; i += 512) d1[i] = s1[i];
    const uint4* s2 = (const uint4*)(fa + (size_t)FO_MS * 512);
    uint4* d2 = (uint4*)ms_lds;
    for (int i = tid; i < 32 * 64; i += 512) d2[i] = s2[i];
    const uint4* s3 = (const uint4*)(fa + (size_t)FO_DECMS * 512);
    uint4* d3 = (uint4*)dms_lds;
    if (tid < 256) d3[tid] = s3[tid];
  }
  for (int i = tid; i < 16 * MS; i += 512) master[i] = 0;

  // ---- preload register weight fragments (pinned against remat)
  bf16x8 be1[6], bp1[5], be2[4], bp2[4], bd2[4], bD[12];
#pragma unroll
  for (int kb = 0; kb < 6; ++kb) {
    be1[kb] = *(const bf16x8*)(fa + (size_t)(FO_ENC1 + w * 6 + kb) * 512 + l * 8);
    pin(be1[kb]);
  }
#pragma unroll
  for (int kb = 0; kb < 5; ++kb) {
    bp1[kb] = *(const bf16x8*)(fa + (size_t)(FO_PRI1 + w * 5 + kb) * 512 + l * 8);
    pin(bp1[kb]);
  }
#pragma unroll
  for (int kb = 0; kb < 4; ++kb) {
    be2[kb] = *(const bf16x8*)(fa + (size_t)(FO_ENC2 + w * 4 + kb) * 512 + l * 8);
    bp2[kb] = *(const bf16x8*)(fa + (size_t)(FO_PRI2 + w * 4 + kb) * 512 + l * 8);
    bd2[kb] = *(const bf16x8*)(fa + (size_t)(FO_DEC2 + w * 4 + kb) * 512 + l * 8);
    pin(be2[kb]); pin(bp2[kb]); pin(bd2[kb]);
  }
  if (w < 4) {
#pragma unroll
    for (int j = 0; j < 2; ++j)
#pragma unroll
      for (int kb = 0; kb < 6; ++kb)
        bD[j * 6 + kb] = *(const bf16x8*)(fa + (size_t)(FO_DEC1 + (w + 4 * j) * 6 + kb) * 512 + l * 8);
  } else {
    int kx = w - 4;
#pragma unroll
    for (int g = 0; g < 3; ++g)
#pragma unroll
      for (int j = 0; j < 2; ++j)
#pragma unroll
        for (int kb = 0; kb < 2; ++kb)
          bD[g * 4 + j * 2 + kb] =
            *(const bf16x8*)(fa + (size_t)(FO_GIH + (g * 8 + kx + 4 * j) * 2 + kb) * 512 + l * 8);
  }
#pragma unroll
  for (int i = 0; i < 12; ++i) pin(bD[i]);

  // ---- preload biases (pinned)
  float eb1v = eb1[a * 128 + w * 16 + ln], pb1v = pb1[a * 128 + w * 16 + ln];
  float eb2v = eb2[a * 128 + w * 16 + ln], pb2v = pb2[a * 128 + w * 16 + ln];
  float db2v = db2[a * 128 + w * 16 + ln];
  float hbm = 0.f, hbs = 0.f, d1b0 = 0.f, d1b1 = 0.f, dmsb = 0.f;
  float ghb[6] = {0.f, 0.f, 0.f, 0.f, 0.f, 0.f};
  if (w < 2) { hbm = emb[a * 32 + w * 16 + ln]; hbs = esb[a * 32 + w * 16 + ln]; }
  else if (w < 4) { hbm = pmb[a * 32 + (w - 2) * 16 + ln]; hbs = psb[a * 32 + (w - 2) * 16 + ln]; }
  if (w < 4) { d1b0 = db1[a * 128 + w * 16 + ln]; d1b1 = db1[a * 128 + (w + 4) * 16 + ln]; }
  else {
    int kx = w - 4;
#pragma unroll
    for (int g = 0; g < 3; ++g)
#pragma unroll
      for (int j = 0; j < 2; ++j)
        ghb[g * 2 + j] = bih[a * 384 + g * 128 + (kx + 4 * j) * 16 + ln]
                       + bhh[a * 384 + g * 128 + (kx + 4 * j) * 16 + ln];
  }
  if (w == 0) dmsb = (ln < 2) ? dmb[a * 2 + ln] : (ln < 4) ? dsb[a * 2 + (ln - 2)] : 0.f;
  pinf(eb1v); pinf(pb1v); pinf(eb2v); pinf(pb2v); pinf(db2v);
  pinf(hbm); pinf(hbs); pinf(d1b0); pinf(d1b1); pinf(dmsb);
#pragma unroll
  for (int i = 0; i < 6; ++i) pinf(ghb[i]);

  __syncthreads();  // master zero done before staging

  // ---- stage y(0), x(0)
  if (tid < 160) {
    int row = tid / 10, c = tid - row * 10;
    master[row * MS + 34 + c] = f2bf(states[(size_t)b0 * 10 + tid]);
  }
  if (tid >= 192 && tid < 224) {
    int i = tid - 192, row = i >> 1, c = i & 1;
    master[row * MS + c] = f2bf(states[((size_t)512 + b0 + row) * 10 + a * 2 + c]);
  }
  float e_cur[4] = {0.f, 0.f, 0.f, 0.f};
  if (w < 2) {
#pragma unroll
    for (int q = 0; q < 4; ++q)
      e_cur[q] = eps[((size_t)(b0 + 4 * lg + q) * 5 + a) * 32 + w * 16 + ln];
  }
  float xv[4] = {0.f, 0.f, 0.f, 0.f};
  float kl = 0.f, nll = 0.f;
  f32x4 em = {0, 0, 0, 0}, esv = {0, 0, 0, 0};
  f32x4 gh[3][2];
  float hn[8];
  __syncthreads();

  for (int t = 0; t < 127; ++t) {
    // ===== Phase A: enc1+pri1 (all); w0 also finishes step t-1 (dec head + NLL) =====
    if (w == 0 && t > 0) {
      f32x4 acc = {dmsb, dmsb, dmsb, dmsb};
#pragma unroll
      for (int kb = 0; kb < 4; ++kb) {
        bf16x8 ad = *(const bf16x8*)&he[ln * TS + kb * 32 + lg * 8];
        bf16x8 bf = *(const bf16x8*)&dms_lds[kb * 512 + l * 8];
        acc = MFMA_B16(ad, bf, acc);
      }
#pragma unroll
      for (int q = 0; q < 4; ++q) {
        float sv = __shfl(splus_(acc[q]), l + 2);
        if (ln < 2) {
          float d = (xv[q] - acc[q]) / sv;
          nll += 0.9189385332f + __logf(sv) + 0.5f * d * d;
        }
      }
    }
    {
      bf16x8 am[6];
#pragma unroll
      for (int kb = 0; kb < 6; ++kb)
        am[kb] = *(const bf16x8*)&master[ln * MS + kb * 32 + lg * 8];
      f32x4 a1 = {eb1v, eb1v, eb1v, eb1v}, a2 = {pb1v, pb1v, pb1v, pb1v};
#pragma unroll
      for (int kb = 0; kb < 6; ++kb) a1 = MFMA_B16(am[kb], be1[kb], a1);
#pragma unroll
      for (int kb = 0; kb < 5; ++kb) a2 = MFMA_B16(am[kb + 1], bp1[kb], a2);
#pragma unroll
      for (int q = 0; q < 4; ++q) {
        t1e[(4 * lg + q) * TS + w * 16 + ln] = f2bf(fmaxf(a1[q], 0.f));
        t1p[(4 * lg + q) * TS + w * 16 + ln] = f2bf(fmaxf(a2[q], 0.f));
      }
    }
    __syncthreads();

    // ===== Phase B: enc2 -> he, pri2 -> hp =====
    {
      bf16x8 ae[4], ap[4];
#pragma unroll
      for (int kb = 0; kb < 4; ++kb) {
        ae[kb] = *(const bf16x8*)&t1e[ln * TS + kb * 32 + lg * 8];
        ap[kb] = *(const bf16x8*)&t1p[ln * TS + kb * 32 + lg * 8];
      }
      f32x4 a1 = {eb2v, eb2v, eb2v, eb2v}, a2 = {pb2v, pb2v, pb2v, pb2v};
#pragma unroll
      for (int kb = 0; kb < 4; ++kb) {
        a1 = MFMA_B16(ae[kb], be2[kb], a1);
        a2 = MFMA_B16(ap[kb], bp2[kb], a2);
      }
#pragma unroll
      for (int q = 0; q < 4; ++q) {
        he[(4 * lg + q) * TS + w * 16 + ln] = f2bf(fmaxf(a1[q], 0.f));
        hp[(4 * lg + q) * TS + w * 16 + ln] = f2bf(fmaxf(a2[q], 0.f));
      }
    }
    __syncthreads();

    // ===== Phase C: heads + z (w0-3), gru_hh (w4-7); eps prefetch for t+1 =====
    {
      float e_nxt[4] = {0.f, 0.f, 0.f, 0.f};
      if (w < 2 && t < 126) {
#pragma unroll
        for (int q = 0; q < 4; ++q)
          e_nxt[q] = eps[((size_t)((t + 1) * 512 + b0 + 4 * lg + q) * 5 + a) * 32 + w * 16 + ln];
      }
      if (w < 4) {
        const unsigned short* hsrc = (w < 2) ? he : hp;
        bf16x8 ah[4];
#pragma unroll
        for (int kb = 0; kb < 4; ++kb)
          ah[kb] = *(const bf16x8*)&hsrc[ln * TS + kb * 32 + lg * 8];
        int mbase = ((w < 2) ? 0 : 16) + (w & 1) * 4;
        f32x4 m = {hbm, hbm, hbm, hbm}, s = {hbs, hbs, hbs, hbs};
#pragma unroll
        for (int kb = 0; kb < 4; ++kb) {
          m = MFMA_B16(ah[kb], *(const bf16x8*)&ms_lds[(mbase + kb) * 512 + l * 8], m);
          s = MFMA_B16(ah[kb], *(const bf16x8*)&ms_lds[(mbase + 8 + kb) * 512 + l * 8], s);
        }
        if (w < 2) {
          em = m;
#pragma unroll
          for (int q = 0; q < 4; ++q) {
            esv[q] = splus_(s[q]);
            master[(4 * lg + q) * MS + 2 + w * 16 + ln] = f2bf(m[q] + esv[q] * e_cur[q]);
          }
        } else {
#pragma unroll
          for (int q = 0; q < 4; ++q) {
            msbuf[0][4 * lg + q][(w - 2) * 16 + ln] = m[q];
            msbuf[1][4 * lg + q][(w - 2) * 16 + ln] = splus_(s[q]);
          }
        }
      } else {
        int kx = w - 4;
        bf16x8 ahh[4];
#pragma unroll
        for (int kb = 0; kb < 4; ++kb)
          ahh[kb] = *(const bf16x8*)&master[ln * MS + (kb + 2) * 32 + lg * 8];
#pragma unroll
        for (int g = 0; g < 3; ++g)
#pragma unroll
          for (int j = 0; j < 2; ++j) {
            float bv = ghb[g * 2 + j];
            gh[g][j] = (f32x4){bv, bv, bv, bv};
          }
#pragma unroll
        for (int kb = 0; kb < 4; ++kb)
#pragma unroll
          for (int g = 0; g < 3; ++g)
#pragma unroll
            for (int j = 0; j < 2; ++j)
              gh[g][j] = MFMA_B16(ahh[kb],
                *(const bf16x8*)&ghh_lds[(size_t)((g * 8 + kx + 4 * j) * 4 + kb) * 512 + l * 8],
                gh[g][j]);
      }
      if (w < 2 && t < 126) {
#pragma unroll
        for (int q = 0; q < 4; ++q) e_cur[q] = e_nxt[q];
      }
    }
    __syncthreads();

    // ===== Phase D: dec1 (w0-3) + KL (w0/1); gru_ih + GRU elementwise (w4-7) =====
    if (w == 0) {
#pragma unroll
      for (int q = 0; q < 4; ++q)
        xv[q] = states[((size_t)(t + 1) * 512 + b0 + 4 * lg + q) * 10 + a * 2 + (ln & 1)];
    }
    if (w < 4) {
      bf16x8 amn[6];
#pragma unroll
      for (int kb = 0; kb < 6; ++kb)
        amn[kb] = *(const bf16x8*)&master[ln * MS + kb * 32 + lg * 8];
#pragma unroll
      for (int j = 0; j < 2; ++j) {
        float bv = (j == 0) ? d1b0 : d1b1;
        f32x4 acc = {bv, bv, bv, bv};
#pragma unroll
        for (int kb = 0; kb < 6; ++kb) acc = MFMA_B16(amn[kb], bD[j * 6 + kb], acc);
#pragma unroll
        for (int q = 0; q < 4; ++q)
          t1e[(4 * lg + q) * TS + (w + 4 * j) * 16 + ln] = f2bf(fmaxf(acc[q], 0.f));
      }
      if (w < 2) {
#pragma unroll
        for (int q = 0; q < 4; ++q) {
          float pm = msbuf[0][4 * lg + q][w * 16 + ln];
          float ps = msbuf[1][4 * lg + q][w * 16 + ln];
          float dm = em[q] - pm;
          float es2 = esv[q] * esv[q];
          kl += 0.5f * (2.f * __logf(ps) - 2.f * __logf(esv[q]) + (es2 + dm * dm) / (ps * ps) - 1.f);
        }
      }
    } else {
      int kx = w - 4;
      bf16x8 am2[2];
#pragma unroll
      for (int kb = 0; kb < 2; ++kb)
        am2[kb] = *(const bf16x8*)&master[ln * MS + kb * 32 + lg * 8];
      f32x4 gi[3][2];
#pragma unroll
      for (int g = 0; g < 3; ++g)
#pragma unroll
        for (int j = 0; j < 2; ++j) gi[g][j] = (f32x4){0.f, 0.f, 0.f, 0.f};
#pragma unroll
      for (int kb = 0; kb < 2; ++kb)
#pragma unroll
        for (int g = 0; g < 3; ++g)
#pragma unroll
          for (int j = 0; j < 2; ++j)
            gi[g][j] = MFMA_B16(am2[kb], bD[g * 4 + j * 2 + kb], gi[g][j]);
#pragma unroll
      for (int j = 0; j < 2; ++j)
#pragma unroll
        for (int q = 0; q < 4; ++q) {
          float r_ = sigm_(gi[0][j][q] + gh[0][j][q]);
          float u_ = sigm_(gi[1][j][q] + gh[1][j][q]);
          float n_ = tanh_(gi[2][j][q] + r_ * gh[2][j][q]);
          float ho = bf2f(master[(4 * lg + q) * MS + 64 + (kx + 4 * j) * 16 + ln]);
          hn[j * 4 + q] = (1.f - u_) * n_ + u_ * ho;
        }
    }
    __syncthreads();

    // ===== Phase E: dec2 -> hd(he); h write; stage y/x(t+1) =====
    {
      bf16x8 ad[4];
#pragma unroll
      for (int kb = 0; kb < 4; ++kb)
        ad[kb] = *(const bf16x8*)&t1e[ln * TS + kb * 32 + lg * 8];
      f32x4 acc = {db2v, db2v, db2v, db2v};
#pragma unroll
      for (int kb = 0; kb < 4; ++kb) acc = MFMA_B16(ad[kb], bd2[kb], acc);
#pragma unroll
      for (int q = 0; q < 4; ++q)
        he[(4 * lg + q) * TS + w * 16 + ln] = f2bf(fmaxf(acc[q], 0.f));
    }
    if (w >= 4) {
      int kx = w - 4;
#pragma unroll
      for (int j = 0; j < 2; ++j)
#pragma unroll
        for (int q = 0; q < 4; ++q)
          master[(4 * lg + q) * MS + 64 + (kx + 4 * j) * 16 + ln] = f2bf(hn[j * 4 + q]);
    }
    if (t < 126) {
      if (w >= 1 && w <= 3) {
        int i = (w - 1) * 64 + l;
        if (i < 160) {
          int row = i / 10, c = i - row * 10;
          master[row * MS + 34 + c] = f2bf(states[((size_t)(t + 1) * 512 + b0) * 10 + i]);
        }
      }
      if (w == 0 && l < 32) {
        int row = l >> 1, c = l & 1;
        master[row * MS + c] = f2bf(states[((size_t)(t + 2) * 512 + b0 + row) * 10 + a * 2 + c]);
      }
    }
    __syncthreads();
  }

  // ---- epilogue: finish step 126 (dec head + NLL) on w0
  if (w == 0) {
    f32x4 acc = {dmsb, dmsb, dmsb, dmsb};
#pragma unroll
    for (int kb = 0; kb < 4; ++kb) {
      bf16x8 ad = *(const bf16x8*)&he[ln * TS + kb * 32 + lg * 8];
      bf16x8 bf = *(const bf16x8*)&dms_lds[kb * 512 + l * 8];
      acc = MFMA_B16(ad, bf, acc);
    }
#pragma unroll
    for (int q = 0; q < 4; ++q) {
      float sv = __shfl(splus_(acc[q]), l + 2);
      if (ln < 2) {
        float d = (xv[q] - acc[q]) / sv;
        nll += 0.9189385332f + __logf(sv) + 0.5f * d * d;
      }
    }
  }

  // ---- final reduction
#pragma unroll
  for (int off = 32; off > 0; off >>= 1) {
    kl += __shfl_down(kl, off);
    nll += __shfl_down(nll, off);
  }
  if (l == 0) { red[w] = kl; red[8 + w] = nll; }
  __syncthreads();
  if (tid == 0) {
    float K = 0.f, N = 0.f;
#pragma unroll
    for (int i = 0; i < 8; ++i) { K += red[i]; N += red[8 + i]; }
    atomicAdd(out, K);
    atomicAdd(out + 1, N);
  }
}

extern "C" void kernel_launch(void* const* d_in, const int* in_sizes, int n_in,
                              void* d_out, int out_size, void* d_ws, size_t ws_size,
                              hipStream_t stream) {
  (void)in_sizes; (void)n_in; (void)out_size; (void)ws_size;
  const float* states = (const float*)d_in[0];
  const float* eps    = (const float*)d_in[1];
  const float* ew1 = (const float*)d_in[2];
  const float* eb1 = (const float*)d_in[3];
  const float* ew2 = (const float*)d_in[4];
  const float* eb2 = (const float*)d_in[5];
  const float* emw = (const float*)d_in[6];
  const float* emb = (const float*)d_in[7];
  const float* esw = (const float*)d_in[8];
  const float* esb = (const float*)d_in[9];
  const float* pw1 = (const float*)d_in[10];
  const float* pb1 = (const float*)d_in[11];
  const float* pw2 = (const float*)d_in[12];
  const float* pb2 = (const float*)d_in[13];
  const float* pmw = (const float*)d_in[14];
  const float* pmb = (const float*)d_in[15];
  const float* psw = (const float*)d_in[16];
  const float* psb = (const float*)d_in[17];
  const float* dw1 = (const float*)d_in[18];
  const float* db1 = (const float*)d_in[19];
  const float* dw2 = (const float*)d_in[20];
  const float* db2 = (const float*)d_in[21];
  const float* dmw = (const float*)d_in[22];
  const float* dmb = (const float*)d_in[23];
  const float* dsw = (const float*)d_in[24];
  const float* dsb = (const float*)d_in[25];
  const float* wih = (const float*)d_in[26];
  const float* whh = (const float*)d_in[27];
  const float* bih = (const float*)d_in[28];
  const float* bhh = (const float*)d_in[29];

  unsigned short* frags = (unsigned short*)d_ws;
  float* out = (float*)d_out;

  hipMemsetAsync(d_out, 0, 2 * sizeof(float), stream);
  prep_kernel<<<dim3(5 * NFRAG), dim3(64), 0, stream>>>(
      ew1, pw1, dw1, wih, whh, ew2, pw2, dw2, emw, esw, pmw, psw, dmw, dsw, frags);
  vrnn_main<<<dim3(32, 5), dim3(512), 0, stream>>>(
      states, eps, eb1, eb2, emb, esb, pb1, pb2, pmb, psb,
      db1, db2, dmb, dsb, bih, bhh, frags, out);
}

// Round 4
// 1089.544 us; speedup vs baseline: 1.0423x; 1.0423x over previous
//
#include <hip/hip_runtime.h>

typedef __attribute__((ext_vector_type(8))) short bf16x8;
typedef __attribute__((ext_vector_type(4))) float f32x4;

#define MFMA_B16(A,B,C) __builtin_amdgcn_mfma_f32_16x16x32_bf16((A),(B),(C),0,0,0)

// ---- fragment layout constants (units: fragments of 1KB = 64 lanes * 8 bf16) ----
#define FO_ENC1 0
#define FO_PRI1 48
#define FO_DEC1 88
#define FO_GIH  136
#define FO_GHH  184
#define FO_ENC2 280
#define FO_PRI2 312
#define FO_DEC2 344
#define FO_MS   376
#define FO_DECMS 408
#define NFRAG   412

// LDS strides in shorts: 100/68 dwords === 4 mod 32 -> b128 reads hit the 8-clk floor (no conflict)
#define MS  200
#define TS  136

__device__ __forceinline__ unsigned short f2bf(float f) {
  union { float f; unsigned u; } v; v.f = f;
  unsigned r = (v.u + 0x7fffu + ((v.u >> 16) & 1u)) >> 16;
  return (unsigned short)r;
}
__device__ __forceinline__ float bf2f(unsigned short h) {
  union { unsigned u; float f; } v; v.u = ((unsigned)h) << 16;
  return v.f;
}
__device__ __forceinline__ float sigm_(float x) { return 1.f / (1.f + __expf(-x)); }
__device__ __forceinline__ float tanh_(float x) {
  x = fminf(fmaxf(x, -15.f), 15.f);
  float e = __expf(-2.f * x);
  return (1.f - e) / (1.f + e);
}
__device__ __forceinline__ float splus_(float x) {
  return fmaxf(x, 0.f) + log1pf(__expf(-fabsf(x)));
}
// pin a value into VGPRs: opaque def defeats rematerialization of the load
__device__ __forceinline__ void pin(bf16x8 &x) {
  f32x4 &r = reinterpret_cast<f32x4&>(x);
  asm volatile("" : "+v"(r));
}
__device__ __forceinline__ void pinf(float &x) { asm volatile("" : "+v"(x)); }

// ============================ PREP KERNEL ============================
// Master activation k-layout: [x:0..1 | z:2..33 | y:34..43 | pad:44..63 | h:64..191]
// Fragment (64 lanes x 8 bf16): lane l, elem j -> B[mk = kb*32 + (l>>4)*8 + j][n = nt*16 + (l&15)]
__global__ void prep_kernel(const float* __restrict__ ew1, const float* __restrict__ pw1,
                            const float* __restrict__ dw1, const float* __restrict__ wih,
                            const float* __restrict__ whh, const float* __restrict__ ew2,
                            const float* __restrict__ pw2, const float* __restrict__ dw2,
                            const float* __restrict__ emw, const float* __restrict__ esw,
                            const float* __restrict__ pmw, const float* __restrict__ psw,
                            const float* __restrict__ dmw, const float* __restrict__ dsw,
                            unsigned short* __restrict__ ws)
{
  int blk = blockIdx.x;
  int a = blk / NFRAG, f = blk % NFRAG;
  int l = threadIdx.x, lg = l >> 4, ln = l & 15;
  float v[8];

  if (f < FO_PRI1) {                       // enc1: rows [x:0-1, y:2-11, h:12-139], N=128
    int fi = f, nt = fi / 6, kb = fi % 6, n = nt * 16 + ln;
#pragma unroll
    for (int j = 0; j < 8; ++j) {
      int mk = kb * 32 + lg * 8 + j;
      int r = (mk < 2) ? mk : (mk >= 34 && mk < 44) ? 2 + (mk - 34)
            : (mk >= 64) ? 12 + (mk - 64) : -1;
      v[j] = (r >= 0) ? ew1[((size_t)a * 140 + r) * 128 + n] : 0.f;
    }
  } else if (f < FO_DEC1) {                // pri1: rows [y:0-9, h:10-137]
    int fi = f - FO_PRI1, nt = fi / 5, kb = 1 + fi % 5, n = nt * 16 + ln;
#pragma unroll
    for (int j = 0; j < 8; ++j) {
      int mk = kb * 32 + lg * 8 + j;
      int r = (mk >= 34 && mk < 44) ? (mk - 34) : (mk >= 64) ? 10 + (mk - 64) : -1;
      v[j] = (r >= 0) ? pw1[((size_t)a * 138 + r) * 128 + n] : 0.f;
    }
  } else if (f < FO_GIH) {                 // dec1: rows [y:0-9, z:10-41, h:42-169]
    int fi = f - FO_DEC1, nt = fi / 6, kb = fi % 6, n = nt * 16 + ln;
#pragma unroll
    for (int j = 0; j < 8; ++j) {
      int mk = kb * 32 + lg * 8 + j;
      int r = (mk >= 2 && mk < 34) ? 10 + (mk - 2) : (mk >= 34 && mk < 44) ? (mk - 34)
            : (mk >= 64) ? 42 + (mk - 64) : -1;
      v[j] = (r >= 0) ? dw1[((size_t)a * 170 + r) * 128 + n] : 0.f;
    }
  } else if (f < FO_GHH) {                 // gru_ih: rows [x:0-1, z:2-33], N=384
    int fi = f - FO_GIH, nt = fi / 2, kb = fi % 2, n = nt * 16 + ln;
#pragma unroll
    for (int j = 0; j < 8; ++j) {
      int mk = kb * 32 + lg * 8 + j;
      v[j] = (mk < 34) ? wih[((size_t)a * 34 + mk) * 384 + n] : 0.f;
    }
  } else if (f < FO_ENC2) {                // gru_hh: K=128 (master kb2..5), N=384
    int fi = f - FO_GHH, nt = fi / 4, kb = fi % 4, n = nt * 16 + ln;
#pragma unroll
    for (int j = 0; j < 8; ++j) {
      int r = kb * 32 + lg * 8 + j;
      v[j] = whh[((size_t)a * 128 + r) * 384 + n];
    }
  } else if (f < FO_DEC2) {                // enc2 / pri2
    int fi = f - FO_ENC2;
    const float* W = (fi < 32) ? ew2 : pw2;
    fi &= 31;
    int nt = fi / 4, kb = fi % 4, n = nt * 16 + ln;
#pragma unroll
    for (int j = 0; j < 8; ++j) {
      int r = kb * 32 + lg * 8 + j;
      v[j] = W[((size_t)a * 128 + r) * 128 + n];
    }
  } else if (f < FO_MS) {                  // dec2
    int fi = f - FO_DEC2, nt = fi / 4, kb = fi % 4, n = nt * 16 + ln;
#pragma unroll
    for (int j = 0; j < 8; ++j) {
      int r = kb * 32 + lg * 8 + j;
      v[j] = dw2[((size_t)a * 128 + r) * 128 + n];
    }
  } else if (f < FO_DECMS) {               // enc_m / enc_s / pri_m / pri_s (N=32)
    int fi = f - FO_MS, mat = fi / 8, rem = fi % 8, nt = rem / 4, kb = rem % 4;
    int n = nt * 16 + ln;
    const float* W = (mat == 0) ? emw : (mat == 1) ? esw : (mat == 2) ? pmw : psw;
#pragma unroll
    for (int j = 0; j < 8; ++j) {
      int r = kb * 32 + lg * 8 + j;
      v[j] = W[((size_t)a * 128 + r) * 32 + n];
    }
  } else {                                 // dec m/s packed: cols 0,1 = mw; 2,3 = sw; rest 0
    int kb = f - FO_DECMS;
#pragma unroll
    for (int j = 0; j < 8; ++j) {
      int r = kb * 32 + lg * 8 + j;
      v[j] = (ln < 2) ? dmw[((size_t)a * 128 + r) * 2 + ln]
           : (ln < 4) ? dsw[((size_t)a * 128 + r) * 2 + (ln - 2)] : 0.f;
    }
  }
  unsigned short* dst = ws + (size_t)blk * 512 + l * 8;
#pragma unroll
  for (int j = 0; j < 8; ++j) dst[j] = f2bf(v[j]);
}

// ============================ MAIN KERNEL ============================
// grid (32, 5): blockIdx.x = batch tile (16 rows), blockIdx.y = agent. 512 threads = 8 waves.
// Weights: ghh/ms/decms pinned in LDS; everything else pinned in registers (asm pin).
// launch_bounds(512, 1): allow up to 256 VGPRs/wave (8-wave block hard-caps at 256 anyway).
// Phases per step (5 barriers): A(enc1,pri1 | w0: prev decms+NLL) | B(enc2,pri2)
//   | C(w0/1: enc heads+z, w2/3: pri heads, w4-7: gru_hh) | D(w0-3: dec1+KL, w4-7: gru_ih+GRU)
//   | E(dec2, h-write, stage y/x(t+1))
__global__ __launch_bounds__(512, 1) void vrnn_main(
    const float* __restrict__ states, const float* __restrict__ eps,
    const float* __restrict__ eb1, const float* __restrict__ eb2,
    const float* __restrict__ emb, const float* __restrict__ esb,
    const float* __restrict__ pb1, const float* __restrict__ pb2,
    const float* __restrict__ pmb, const float* __restrict__ psb,
    const float* __restrict__ db1, const float* __restrict__ db2,
    const float* __restrict__ dmb, const float* __restrict__ dsb,
    const float* __restrict__ bih, const float* __restrict__ bhh,
    const unsigned short* __restrict__ frags, float* __restrict__ out)
{
  const int a = blockIdx.y;
  const int b0 = blockIdx.x * 16;
  const int tid = threadIdx.x;
  const int w = tid >> 6, l = tid & 63, lg = l >> 4, ln = l & 15;

  __shared__ __align__(16) unsigned short ghh_lds[96 * 512];
  __shared__ __align__(16) unsigned short ms_lds[32 * 512];
  __shared__ __align__(16) unsigned short dms_lds[4 * 512];
  __shared__ __align__(16) unsigned short master[16 * MS];
  __shared__ __align__(16) unsigned short t1e[16 * TS], t1p[16 * TS];  // t1d aliases t1e
  __shared__ __align__(16) unsigned short he[16 * TS], hp[16 * TS];    // hd aliases he
  __shared__ float msbuf[2][16][32];
  __shared__ float red[16];

  const unsigned short* fa = frags + (size_t)a * NFRAG * 512;

  // ---- pin LDS weight sets (once)
  {
    const uint4* s1 = (const uint4*)(fa + (size_t)FO_GHH * 512);
    uint4* d1 = (uint4*)ghh_lds;
    for (int i = tid; i < 96 * 64; i += 512) d1[i] = s1[i];
    const uint4* s2 = (const uint4*)(fa + (size_t)FO_MS * 512);
    uint4* d2 = (uint4*)ms_lds;
    for (int i = tid; i < 32 * 64; i += 512) d2[i] = s2[i];
    const uint4* s3 = (const uint4*)(fa + (size_t)FO_DECMS * 512);
    uint4* d3 = (uint4*)dms_lds;
    if (tid < 256) d3[tid] = s3[tid];
  }
  for (int i = tid; i < 16 * MS; i += 512) master[i] = 0;

  // ---- preload register weight fragments (pinned against remat)
  bf16x8 be1[6], bp1[5], be2[4], bp2[4], bd2[4], bD[12];
#pragma unroll
  for (int kb = 0; kb < 6; ++kb) {
    be1[kb] = *(const bf16x8*)(fa + (size_t)(FO_ENC1 + w * 6 + kb) * 512 + l * 8);
    pin(be1[kb]);
  }
#pragma unroll
  for (int kb = 0; kb < 5; ++kb) {
    bp1[kb] = *(const bf16x8*)(fa + (size_t)(FO_PRI1 + w * 5 + kb) * 512 + l * 8);
    pin(bp1[kb]);
  }
#pragma unroll
  for (int kb = 0; kb < 4; ++kb) {
    be2[kb] = *(const bf16x8*)(fa + (size_t)(FO_ENC2 + w * 4 + kb) * 512 + l * 8);
    bp2[kb] = *(const bf16x8*)(fa + (size_t)(FO_PRI2 + w * 4 + kb) * 512 + l * 8);
    bd2[kb] = *(const bf16x8*)(fa + (size_t)(FO_DEC2 + w * 4 + kb) * 512 + l * 8);
    pin(be2[kb]); pin(bp2[kb]); pin(bd2[kb]);
  }
  if (w < 4) {
#pragma unroll
    for (int j = 0; j < 2; ++j)
#pragma unroll
      for (int kb = 0; kb < 6; ++kb)
        bD[j * 6 + kb] = *(const bf16x8*)(fa + (size_t)(FO_DEC1 + (w + 4 * j) * 6 + kb) * 512 + l * 8);
  } else {
    int kx = w - 4;
#pragma unroll
    for (int g = 0; g < 3; ++g)
#pragma unroll
      for (int j = 0; j < 2; ++j)
#pragma unroll
        for (int kb = 0; kb < 2; ++kb)
          bD[g * 4 + j * 2 + kb] =
            *(const bf16x8*)(fa + (size_t)(FO_GIH + (g * 8 + kx + 4 * j) * 2 + kb) * 512 + l * 8);
  }
#pragma unroll
  for (int i = 0; i < 12; ++i) pin(bD[i]);

  // ---- preload biases (pinned)
  float eb1v = eb1[a * 128 + w * 16 + ln], pb1v = pb1[a * 128 + w * 16 + ln];
  float eb2v = eb2[a * 128 + w * 16 + ln], pb2v = pb2[a * 128 + w * 16 + ln];
  float db2v = db2[a * 128 + w * 16 + ln];
  float hbm = 0.f, hbs = 0.f, d1b0 = 0.f, d1b1 = 0.f, dmsb = 0.f;
  float ghb[6] = {0.f, 0.f, 0.f, 0.f, 0.f, 0.f};
  if (w < 2) { hbm = emb[a * 32 + w * 16 + ln]; hbs = esb[a * 32 + w * 16 + ln]; }
  else if (w < 4) { hbm = pmb[a * 32 + (w - 2) * 16 + ln]; hbs = psb[a * 32 + (w - 2) * 16 + ln]; }
  if (w < 4) { d1b0 = db1[a * 128 + w * 16 + ln]; d1b1 = db1[a * 128 + (w + 4) * 16 + ln]; }
  else {
    int kx = w - 4;
#pragma unroll
    for (int g = 0; g < 3; ++g)
#pragma unroll
      for (int j = 0; j < 2; ++j)
        ghb[g * 2 + j] = bih[a * 384 + g * 128 + (kx + 4 * j) * 16 + ln]
                       + bhh[a * 384 + g * 128 + (kx + 4 * j) * 16 + ln];
  }
  if (w == 0) dmsb = (ln < 2) ? dmb[a * 2 + ln] : (ln < 4) ? dsb[a * 2 + (ln - 2)] : 0.f;
  pinf(eb1v); pinf(pb1v); pinf(eb2v); pinf(pb2v); pinf(db2v);
  pinf(hbm); pinf(hbs); pinf(d1b0); pinf(d1b1); pinf(dmsb);
#pragma unroll
  for (int i = 0; i < 6; ++i) pinf(ghb[i]);

  __syncthreads();  // master zero done before staging

  // ---- stage y(0), x(0)
  if (tid < 160) {
    int row = tid / 10, c = tid - row * 10;
    master[row * MS + 34 + c] = f2bf(states[(size_t)b0 * 10 + tid]);
  }
  if (tid >= 192 && tid < 224) {
    int i = tid - 192, row = i >> 1, c = i & 1;
    master[row * MS + c] = f2bf(states[((size_t)512 + b0 + row) * 10 + a * 2 + c]);
  }
  float e_cur[4] = {0.f, 0.f, 0.f, 0.f};
  if (w < 2) {
#pragma unroll
    for (int q = 0; q < 4; ++q)
      e_cur[q] = eps[((size_t)(b0 + 4 * lg + q) * 5 + a) * 32 + w * 16 + ln];
  }
  float xv[4] = {0.f, 0.f, 0.f, 0.f};
  float kl = 0.f, nll = 0.f;
  f32x4 em = {0, 0, 0, 0}, esv = {0, 0, 0, 0};
  f32x4 gh[3][2];
  float hn[8];
  __syncthreads();

  for (int t = 0; t < 127; ++t) {
    // ===== Phase A: enc1+pri1 (all); w0 also finishes step t-1 (dec head + NLL) =====
    if (w == 0 && t > 0) {
      f32x4 acc = {dmsb, dmsb, dmsb, dmsb};
#pragma unroll
      for (int kb = 0; kb < 4; ++kb) {
        bf16x8 ad = *(const bf16x8*)&he[ln * TS + kb * 32 + lg * 8];
        bf16x8 bf = *(const bf16x8*)&dms_lds[kb * 512 + l * 8];
        acc = MFMA_B16(ad, bf, acc);
      }
#pragma unroll
      for (int q = 0; q < 4; ++q) {
        float sv = __shfl(splus_(acc[q]), l + 2);
        if (ln < 2) {
          float d = (xv[q] - acc[q]) / sv;
          nll += 0.9189385332f + __logf(sv) + 0.5f * d * d;
        }
      }
    }
    {
      bf16x8 am[6];
#pragma unroll
      for (int kb = 0; kb < 6; ++kb)
        am[kb] = *(const bf16x8*)&master[ln * MS + kb * 32 + lg * 8];
      f32x4 a1 = {eb1v, eb1v, eb1v, eb1v}, a2 = {pb1v, pb1v, pb1v, pb1v};
#pragma unroll
      for (int kb = 0; kb < 6; ++kb) a1 = MFMA_B16(am[kb], be1[kb], a1);
#pragma unroll
      for (int kb = 0; kb < 5; ++kb) a2 = MFMA_B16(am[kb + 1], bp1[kb], a2);
#pragma unroll
      for (int q = 0; q < 4; ++q) {
        t1e[(4 * lg + q) * TS + w * 16 + ln] = f2bf(fmaxf(a1[q], 0.f));
        t1p[(4 * lg + q) * TS + w * 16 + ln] = f2bf(fmaxf(a2[q], 0.f));
      }
    }
    __syncthreads();

    // ===== Phase B: enc2 -> he, pri2 -> hp =====
    {
      bf16x8 ae[4], ap[4];
#pragma unroll
      for (int kb = 0; kb < 4; ++kb) {
        ae[kb] = *(const bf16x8*)&t1e[ln * TS + kb * 32 + lg * 8];
        ap[kb] = *(const bf16x8*)&t1p[ln * TS + kb * 32 + lg * 8];
      }
      f32x4 a1 = {eb2v, eb2v, eb2v, eb2v}, a2 = {pb2v, pb2v, pb2v, pb2v};
#pragma unroll
      for (int kb = 0; kb < 4; ++kb) {
        a1 = MFMA_B16(ae[kb], be2[kb], a1);
        a2 = MFMA_B16(ap[kb], bp2[kb], a2);
      }
#pragma unroll
      for (int q = 0; q < 4; ++q) {
        he[(4 * lg + q) * TS + w * 16 + ln] = f2bf(fmaxf(a1[q], 0.f));
        hp[(4 * lg + q) * TS + w * 16 + ln] = f2bf(fmaxf(a2[q], 0.f));
      }
    }
    __syncthreads();

    // ===== Phase C: heads + z (w0-3), gru_hh (w4-7); eps prefetch for t+1 =====
    {
      float e_nxt[4] = {0.f, 0.f, 0.f, 0.f};
      if (w < 2 && t < 126) {
#pragma unroll
        for (int q = 0; q < 4; ++q)
          e_nxt[q] = eps[((size_t)((t + 1) * 512 + b0 + 4 * lg + q) * 5 + a) * 32 + w * 16 + ln];
      }
      if (w < 4) {
        const unsigned short* hsrc = (w < 2) ? he : hp;
        bf16x8 ah[4];
#pragma unroll
        for (int kb = 0; kb < 4; ++kb)
          ah[kb] = *(const bf16x8*)&hsrc[ln * TS + kb * 32 + lg * 8];
        int mbase = ((w < 2) ? 0 : 16) + (w & 1) * 4;
        f32x4 m = {hbm, hbm, hbm, hbm}, s = {hbs, hbs, hbs, hbs};
#pragma unroll
        for (int kb = 0; kb < 4; ++kb) {
          m = MFMA_B16(ah[kb], *(const bf16x8*)&ms_lds[(mbase + kb) * 512 + l * 8], m);
          s = MFMA_B16(ah[kb], *(const bf16x8*)&ms_lds[(mbase + 8 + kb) * 512 + l * 8], s);
        }
        if (w < 2) {
          em = m;
#pragma unroll
          for (int q = 0; q < 4; ++q) {
            esv[q] = splus_(s[q]);
            master[(4 * lg + q) * MS + 2 + w * 16 + ln] = f2bf(m[q] + esv[q] * e_cur[q]);
          }
        } else {
#pragma unroll
          for (int q = 0; q < 4; ++q) {
            msbuf[0][4 * lg + q][(w - 2) * 16 + ln] = m[q];
            msbuf[1][4 * lg + q][(w - 2) * 16 + ln] = splus_(s[q]);
          }
        }
      } else {
        int kx = w - 4;
        bf16x8 ahh[4];
#pragma unroll
        for (int kb = 0; kb < 4; ++kb)
          ahh[kb] = *(const bf16x8*)&master[ln * MS + (kb + 2) * 32 + lg * 8];
#pragma unroll
        for (int g = 0; g < 3; ++g)
#pragma unroll
          for (int j = 0; j < 2; ++j) {
            float bv = ghb[g * 2 + j];
            gh[g][j] = (f32x4){bv, bv, bv, bv};
          }
#pragma unroll
        for (int kb = 0; kb < 4; ++kb)
#pragma unroll
          for (int g = 0; g < 3; ++g)
#pragma unroll
            for (int j = 0; j < 2; ++j)
              gh[g][j] = MFMA_B16(ahh[kb],
                *(const bf16x8*)&ghh_lds[(size_t)((g * 8 + kx + 4 * j) * 4 + kb) * 512 + l * 8],
                gh[g][j]);
      }
      if (w < 2 && t < 126) {
#pragma unroll
        for (int q = 0; q < 4; ++q) e_cur[q] = e_nxt[q];
      }
    }
    __syncthreads();

    // ===== Phase D: dec1 (w0-3) + KL (w0/1); gru_ih + GRU elementwise (w4-7) =====
    if (w == 0) {
#pragma unroll
      for (int q = 0; q < 4; ++q)
        xv[q] = states[((size_t)(t + 1) * 512 + b0 + 4 * lg + q) * 10 + a * 2 + (ln & 1)];
    }
    if (w < 4) {
      bf16x8 amn[6];
#pragma unroll
      for (int kb = 0; kb < 6; ++kb)
        amn[kb] = *(const bf16x8*)&master[ln * MS + kb * 32 + lg * 8];
#pragma unroll
      for (int j = 0; j < 2; ++j) {
        float bv = (j == 0) ? d1b0 : d1b1;
        f32x4 acc = {bv, bv, bv, bv};
#pragma unroll
        for (int kb = 0; kb < 6; ++kb) acc = MFMA_B16(amn[kb], bD[j * 6 + kb], acc);
#pragma unroll
        for (int q = 0; q < 4; ++q)
          t1e[(4 * lg + q) * TS + (w + 4 * j) * 16 + ln] = f2bf(fmaxf(acc[q], 0.f));
      }
      if (w < 2) {
#pragma unroll
        for (int q = 0; q < 4; ++q) {
          float pm = msbuf[0][4 * lg + q][w * 16 + ln];
          float ps = msbuf[1][4 * lg + q][w * 16 + ln];
          float dm = em[q] - pm;
          float es2 = esv[q] * esv[q];
          kl += 0.5f * (2.f * __logf(ps) - 2.f * __logf(esv[q]) + (es2 + dm * dm) / (ps * ps) - 1.f);
        }
      }
    } else {
      int kx = w - 4;
      bf16x8 am2[2];
#pragma unroll
      for (int kb = 0; kb < 2; ++kb)
        am2[kb] = *(const bf16x8*)&master[ln * MS + kb * 32 + lg * 8];
      f32x4 gi[3][2];
#pragma unroll
      for (int g = 0; g < 3; ++g)
#pragma unroll
        for (int j = 0; j < 2; ++j) gi[g][j] = (f32x4){0.f, 0.f, 0.f, 0.f};
#pragma unroll
      for (int kb = 0; kb < 2; ++kb)
#pragma unroll
        for (int g = 0; g < 3; ++g)
#pragma unroll
          for (int j = 0; j < 2; ++j)
            gi[g][j] = MFMA_B16(am2[kb], bD[g * 4 + j * 2 + kb], gi[g][j]);
#pragma unroll
      for (int j = 0; j < 2; ++j)
#pragma unroll
        for (int q = 0; q < 4; ++q) {
          float r_ = sigm_(gi[0][j][q] + gh[0][j][q]);
          float u_ = sigm_(gi[1][j][q] + gh[1][j][q]);
          float n_ = tanh_(gi[2][j][q] + r_ * gh[2][j][q]);
          float ho = bf2f(master[(4 * lg + q) * MS + 64 + (kx + 4 * j) * 16 + ln]);
          hn[j * 4 + q] = (1.f - u_) * n_ + u_ * ho;
        }
    }
    __syncthreads();

    // ===== Phase E: dec2 -> hd(he); h write; stage y/x(t+1) =====
    {
      bf16x8 ad[4];
#pragma unroll
      for (int kb = 0; kb < 4; ++kb)
        ad[kb] = *(const bf16x8*)&t1e[ln * TS + kb * 32 + lg * 8];
      f32x4 acc = {db2v, db2v, db2v, db2v};
#pragma unroll
      for (int kb = 0; kb < 4; ++kb) acc = MFMA_B16(ad[kb], bd2[kb], acc);
#pragma unroll
      for (int q = 0; q < 4; ++q)
        he[(4 * lg + q) * TS + w * 16 + ln] = f2bf(fmaxf(acc[q], 0.f));
    }
    if (w >= 4) {
      int kx = w - 4;
#pragma unroll
      for (int j = 0; j < 2; ++j)
#pragma unroll
        for (int q = 0; q < 4; ++q)
          master[(4 * lg + q) * MS + 64 + (kx + 4 * j) * 16 + ln] = f2bf(hn[j * 4 + q]);
    }
    if (t < 126) {
      if (w >= 1 && w <= 3) {
        int i = (w - 1) * 64 + l;
        if (i < 160) {
          int row = i / 10, c = i - row * 10;
          master[row * MS + 34 + c] = f2bf(states[((size_t)(t + 1) * 512 + b0) * 10 + i]);
        }
      }
      if (w == 0 && l < 32) {
        int row = l >> 1, c = l & 1;
        master[row * MS + c] = f2bf(states[((size_t)(t + 2) * 512 + b0 + row) * 10 + a * 2 + c]);
      }
    }
    __syncthreads();
  }

  // ---- epilogue: finish step 126 (dec head + NLL) on w0
  if (w == 0) {
    f32x4 acc = {dmsb, dmsb, dmsb, dmsb};
#pragma unroll
    for (int kb = 0; kb < 4; ++kb) {
      bf16x8 ad = *(const bf16x8*)&he[ln * TS + kb * 32 + lg * 8];
      bf16x8 bf = *(const bf16x8*)&dms_lds[kb * 512 + l * 8];
      acc = MFMA_B16(ad, bf, acc);
    }
#pragma unroll
    for (int q = 0; q < 4; ++q) {
      float sv = __shfl(splus_(acc[q]), l + 2);
      if (ln < 2) {
        float d = (xv[q] - acc[q]) / sv;
        nll += 0.9189385332f + __logf(sv) + 0.5f * d * d;
      }
    }
  }

  // ---- final reduction
#pragma unroll
  for (int off = 32; off > 0; off >>= 1) {
    kl += __shfl_down(kl, off);
    nll += __shfl_down(nll, off);
  }
  if (l == 0) { red[w] = kl; red[8 + w] = nll; }
  __syncthreads();
  if (tid == 0) {
    float K = 0.f, N = 0.f;
#pragma unroll
    for (int i = 0; i < 8; ++i) { K += red[i]; N += red[8 + i]; }
    atomicAdd(out, K);
    atomicAdd(out + 1, N);
  }
}

extern "C" void kernel_launch(void* const* d_in, const int* in_sizes, int n_in,
                              void* d_out, int out_size, void* d_ws, size_t ws_size,
                              hipStream_t stream) {
  (void)in_sizes; (void)n_in; (void)out_size; (void)ws_size;
  const float* states = (const float*)d_in[0];
  const float* eps    = (const float*)d_in[1];
  const float* ew1 = (const float*)d_in[2];
  const float* eb1 = (const float*)d_in[3];
  const float* ew2 = (const float*)d_in[4];
  const float* eb2 = (const float*)d_in[5];
  const float* emw = (const float*)d_in[6];
  const float* emb = (const float*)d_in[7];
  const float* esw = (const float*)d_in[8];
  const float* esb = (const float*)d_in[9];
  const float* pw1 = (const float*)d_in[10];
  const float* pb1 = (const float*)d_in[11];
  const float* pw2 = (const float*)d_in[12];
  const float* pb2 = (const float*)d_in[13];
  const float* pmw = (const float*)d_in[14];
  const float* pmb = (const float*)d_in[15];
  const float* psw = (const float*)d_in[16];
  const float* psb = (const float*)d_in[17];
  const float* dw1 = (const float*)d_in[18];
  const float* db1 = (const float*)d_in[19];
  const float* dw2 = (const float*)d_in[20];
  const float* db2 = (const float*)d_in[21];
  const float* dmw = (const float*)d_in[22];
  const float* dmb = (const float*)d_in[23];
  const float* dsw = (const float*)d_in[24];
  const float* dsb = (const float*)d_in[25];
  const float* wih = (const float*)d_in[26];
  const float* whh = (const float*)d_in[27];
  const float* bih = (const float*)d_in[28];
  const float* bhh = (const float*)d_in[29];

  unsigned short* frags = (unsigned short*)d_ws;
  float* out = (float*)d_out;

  hipMemsetAsync(d_out, 0, 2 * sizeof(float), stream);
  prep_kernel<<<dim3(5 * NFRAG), dim3(64), 0, stream>>>(
      ew1, pw1, dw1, wih, whh, ew2, pw2, dw2, emw, esw, pmw, psw, dmw, dsw, frags);
  vrnn_main<<<dim3(32, 5), dim3(512), 0, stream>>>(
      states, eps, eb1, eb2, emb, esb, pb1, pb2, pmb, psb,
      db1, db2, dmb, dsb, bih, bhh, frags, out);
}